// Round 20
// baseline (153.234 us; speedup 1.0000x reference)
//
#include <hip/hip_runtime.h>

#define B_ 2048
#define T_ 200
#define D_ 64

constexpr int ROWS = 8;           // valid batch rows per block (MFMA M=16, 8 pad)
constexpr int NBLK = B_ / ROWS;   // 256 blocks -> 1 per CU, ALL CUs busy
constexpr int NTHR = 320;         // 5 waves: 2 consumers + 2 producers + 1 writer

typedef _Float16 half_t;
typedef __attribute__((ext_vector_type(8))) _Float16 h8;
typedef __attribute__((ext_vector_type(4))) float f32x4;

// 16x16x32 f16 MFMA fragment layouts [HW-verified r9/r11/r12]:
// A: lane l holds A[row=l&15][k=(l>>4)*8+j]
// B: lane l holds B[k=(l>>4)*8+j][col=l&15]
// C/D: lane l holds D[row=(l>>4)*4+reg][col=l&15]
__device__ __forceinline__ f32x4 MF(h8 a, h8 b, f32x4 c) {
  return __builtin_amdgcn_mfma_f32_16x16x32_f16(a, b, c, 0, 0, 0);
}

__device__ __forceinline__ float rcp_(float x) { return __builtin_amdgcn_rcpf(x); }
__device__ __forceinline__ float sigmoidf_(float x) { return rcp_(1.0f + __expf(-x)); }
__device__ __forceinline__ float tanhf_(float x) {
  x = fminf(fmaxf(x, -15.0f), 15.0f);
  const float e = __expf(2.0f * x);
  return (e - 1.0f) * rcp_(e + 1.0f);
}

__device__ __forceinline__ h8 loadB(const float* __restrict__ W, int stride,
                                    int k0, int col) {
  h8 v;
#pragma unroll
  for (int j = 0; j < 8; ++j) v[j] = (half_t)W[(k0 + j) * stride + col];
  return v;
}

// Producer/writer barrier: LDS-ordering only; global loads/stores stay in
// flight (r18/19-validated mixing with consumers' __syncthreads).
#define RBAR() asm volatile("s_waitcnt lgkmcnt(0)\n\ts_barrier" ::: "memory")

__global__ __launch_bounds__(NTHR, 1)
void augru_pcw2(const float* __restrict__ X, const int* __restrict__ SL,
                const float* __restrict__ ATT, const float* __restrict__ Wg,
                const float* __restrict__ bg, const float* __restrict__ Wc,
                const float* __restrict__ bc, float* __restrict__ OUT) {
  __shared__ __align__(16) half_t sAh[2][512];     // h, A-layout fp16 (2 k-slices)
  __shared__ __align__(16) half_t sRh[2][512];     // r*h, A-layout fp16
  __shared__ __align__(16) f32x4 sPre[2][12][64];  // x-preacts, D-layout (24KB)
  __shared__ __align__(16) float sAtt[T_][8];      // att table (6.4KB)

  const int tid = threadIdx.x;
  const int wv = tid >> 6;
  const int l = tid & 63;
  const int b0 = blockIdx.x * ROWS;
  const int rA = l & 15;
  const int kq = l >> 4;

  int Lm = 1;
  for (int r = 0; r < ROWS; ++r) {
    const int v = SL[b0 + r];
    Lm = v > Lm ? v : Lm;
  }

  // one-time: att table + zero h staging
  for (int i = tid; i < ROWS * T_; i += NTHR) {
    const int r = i / T_;
    const int t0_ = i - r * T_;
    sAtt[t0_][r] = ATT[(size_t)(b0 + r) * T_ + t0_];
  }
  if (tid < 128) {
    h8 z;
#pragma unroll
    for (int j = 0; j < 8; ++j) z[j] = (half_t)0.f;
    ((h8*)&sAh[0][0])[tid] = z;
  }

  if (wv < 2) {
    // ===================== CONSUMERS (2 waves, 32 cols each) ================
    const int w = wv;
    const int rowD = kq * 4;
    const int cA = 32 * w + rA;       // tile0 col
    const int cB = cA + 16;           // tile1 col

    // h-part weights: 12 B-frags = 48 VGPRs (proven resident)
    const h8 wr0a = loadB(Wg, 128, 64 + kq * 8, cA);
    const h8 wr0b = loadB(Wg, 128, 96 + kq * 8, cA);
    const h8 wr1a = loadB(Wg, 128, 64 + kq * 8, cB);
    const h8 wr1b = loadB(Wg, 128, 96 + kq * 8, cB);
    const h8 wu0a = loadB(Wg, 128, 64 + kq * 8, 64 + cA);
    const h8 wu0b = loadB(Wg, 128, 96 + kq * 8, 64 + cA);
    const h8 wu1a = loadB(Wg, 128, 64 + kq * 8, 64 + cB);
    const h8 wu1b = loadB(Wg, 128, 96 + kq * 8, 64 + cB);
    const h8 wc0a = loadB(Wc, 64, 64 + kq * 8, cA);
    const h8 wc0b = loadB(Wc, 64, 96 + kq * 8, cA);
    const h8 wc1a = loadB(Wc, 64, 64 + kq * 8, cB);
    const h8 wc1b = loadB(Wc, 64, 96 + kq * 8, cB);

    // A-layout staging bases within k-slice w (halfs; +8 per row)
    const int kpA = rA;
    const int baseA = (rowD + 16 * (kpA >> 3)) * 8 + (kpA & 7);
    const int kpB = 16 + rA;
    const int baseB = (rowD + 16 * (kpB >> 3)) * 8 + (kpB & 7);

    const int L0 = SL[b0 + ((rowD + 0 < ROWS) ? rowD + 0 : ROWS - 1)];
    const int L1 = SL[b0 + ((rowD + 1 < ROWS) ? rowD + 1 : ROWS - 1)];
    const int L2 = SL[b0 + ((rowD + 2 < ROWS) ? rowD + 2 : ROWS - 1)];
    const int L3 = SL[b0 + ((rowD + 3 < ROWS) ? rowD + 3 : ROWS - 1)];

    const f32x4 z4 = {0.f, 0.f, 0.f, 0.f};
    f32x4 hd0 = z4, hd1 = z4;  // f32 state, tile0/tile1 cols, rows rowD..+3

    __syncthreads();  // prologue (drains weight/SL/att loads once)

    for (int t = 0; t < Lm; ++t) {
      const int tb = t & 1;
      const h8 ah0 = ((const h8*)&sAh[0][0])[l];
      const h8 ah1 = ((const h8*)&sAh[1][0])[l];
      const f32x4 grx0 = sPre[tb][6 * w + 0][l];
      const f32x4 grx1 = sPre[tb][6 * w + 1][l];
      const f32x4 gux0 = sPre[tb][6 * w + 2][l];
      const f32x4 gux1 = sPre[tb][6 * w + 3][l];
      const f32x4 ccx0 = sPre[tb][6 * w + 4][l];
      const f32x4 ccx1 = sPre[tb][6 * w + 5][l];
      const f32x4 atv = *(const f32x4*)&sAtt[t][rowD & 7];

      // r gates: h-dep depth 1 (parallel MFMA + add)
      const f32x4 gr0 = MF(ah0, wr0a, grx0) + MF(ah1, wr0b, z4);
      const f32x4 gr1 = MF(ah0, wr1a, grx1) + MF(ah1, wr1b, z4);
      sRh[w][baseA + 0]  = (half_t)(sigmoidf_(gr0[0]) * hd0[0]);
      sRh[w][baseA + 8]  = (half_t)(sigmoidf_(gr0[1]) * hd0[1]);
      sRh[w][baseA + 16] = (half_t)(sigmoidf_(gr0[2]) * hd0[2]);
      sRh[w][baseA + 24] = (half_t)(sigmoidf_(gr0[3]) * hd0[3]);
      sRh[w][baseB + 0]  = (half_t)(sigmoidf_(gr1[0]) * hd1[0]);
      sRh[w][baseB + 8]  = (half_t)(sigmoidf_(gr1[1]) * hd1[1]);
      sRh[w][baseB + 16] = (half_t)(sigmoidf_(gr1[2]) * hd1[2]);
      sRh[w][baseB + 24] = (half_t)(sigmoidf_(gr1[3]) * hd1[3]);

      // u gates + att scale (phase-1 filler, off the rh path)
      const f32x4 gu0 = MF(ah0, wu0a, gux0) + MF(ah1, wu0b, z4);
      const f32x4 gu1 = MF(ah0, wu1a, gux1) + MF(ah1, wu1b, z4);
      f32x4 ua0, ua1;
#pragma unroll
      for (int i = 0; i < 4; ++i) {
        ua0[i] = atv[i] * sigmoidf_(gu0[i]);
        ua1[i] = atv[i] * sigmoidf_(gu1[i]);
      }

      __syncthreads();  // B1 (free: consumers have no VMEM outstanding)

      const h8 arh0 = ((const h8*)&sRh[0][0])[l];
      const h8 arh1 = ((const h8*)&sRh[1][0])[l];
      const f32x4 cc0 = MF(arh0, wc0a, ccx0) + MF(arh1, wc0b, z4);
      const f32x4 cc1 = MF(arh0, wc1a, ccx1) + MF(arh1, wc1b, z4);

#define FIN(i, CC, UA, HD, BASE, LI)                       \
  {                                                        \
    const float cv = tanhf_(CC[i]);                        \
    const float hp = HD[i];                                \
    const float hn = fmaf(UA[i], cv - hp, hp);             \
    HD[i] = (t < LI) ? hn : hp;                            \
    sAh[w][BASE + (i)*8] = (half_t)HD[i];                  \
  }
      FIN(0, cc0, ua0, hd0, baseA, L0)
      FIN(1, cc0, ua0, hd0, baseA, L1)
      FIN(2, cc0, ua0, hd0, baseA, L2)
      FIN(3, cc0, ua0, hd0, baseA, L3)
      FIN(0, cc1, ua1, hd1, baseB, L0)
      FIN(1, cc1, ua1, hd1, baseB, L1)
      FIN(2, cc1, ua1, hd1, baseB, L2)
      FIN(3, cc1, ua1, hd1, baseB, L3)
#undef FIN

      __syncthreads();  // B2
    }
  } else if (wv < 4) {
    // ===================== PRODUCERS (2 waves, 32 cols each) ================
    const int p = wv - 2;
    const int g0 = 32 * p + rA;

    const h8 pr0a = loadB(Wg, 128, 0 + kq * 8, g0);
    const h8 pr0b = loadB(Wg, 128, 32 + kq * 8, g0);
    const h8 pr1a = loadB(Wg, 128, 0 + kq * 8, g0 + 16);
    const h8 pr1b = loadB(Wg, 128, 32 + kq * 8, g0 + 16);
    const h8 pu0a = loadB(Wg, 128, 0 + kq * 8, 64 + g0);
    const h8 pu0b = loadB(Wg, 128, 32 + kq * 8, 64 + g0);
    const h8 pu1a = loadB(Wg, 128, 0 + kq * 8, 64 + g0 + 16);
    const h8 pu1b = loadB(Wg, 128, 32 + kq * 8, 64 + g0 + 16);
    const h8 pc0a = loadB(Wc, 64, 0 + kq * 8, g0);
    const h8 pc0b = loadB(Wc, 64, 32 + kq * 8, g0);
    const h8 pc1a = loadB(Wc, 64, 0 + kq * 8, g0 + 16);
    const h8 pc1b = loadB(Wc, 64, 32 + kq * 8, g0 + 16);
    const float fbr0 = bg[g0], fbr1 = bg[g0 + 16];
    const float fbu0 = bg[64 + g0], fbu1 = bg[64 + g0 + 16];
    const float fbc0 = bc[g0], fbc1 = bc[g0 + 16];

    const int xr = (rA < ROWS) ? rA : ROWS - 1;  // clamp pad A-rows (finite)
    const float* __restrict__ xrow = X + (size_t)(b0 + xr) * (T_ * D_);

#define PEMIT(AX0, AX1, NB)                                 \
  {                                                         \
    f32x4 a;                                                \
    a = (f32x4){fbr0, fbr0, fbr0, fbr0};                    \
    a = MF(AX0, pr0a, a); a = MF(AX1, pr0b, a);             \
    sPre[NB][6 * p + 0][l] = a;                             \
    a = (f32x4){fbr1, fbr1, fbr1, fbr1};                    \
    a = MF(AX0, pr1a, a); a = MF(AX1, pr1b, a);             \
    sPre[NB][6 * p + 1][l] = a;                             \
    a = (f32x4){fbu0, fbu0, fbu0, fbu0};                    \
    a = MF(AX0, pu0a, a); a = MF(AX1, pu0b, a);             \
    sPre[NB][6 * p + 2][l] = a;                             \
    a = (f32x4){fbu1, fbu1, fbu1, fbu1};                    \
    a = MF(AX0, pu1a, a); a = MF(AX1, pu1b, a);             \
    sPre[NB][6 * p + 3][l] = a;                             \
    a = (f32x4){fbc0, fbc0, fbc0, fbc0};                    \
    a = MF(AX0, pc0a, a); a = MF(AX1, pc0b, a);             \
    sPre[NB][6 * p + 4][l] = a;                             \
    a = (f32x4){fbc1, fbc1, fbc1, fbc1};                    \
    a = MF(AX0, pc1a, a); a = MF(AX1, pc1b, a);             \
    sPre[NB][6 * p + 5][l] = a;                             \
  }

    // prologue: preact(0) -> buf0; then prefetch x(1)
    {
      const f32x4 a0 = *(const f32x4*)(xrow + kq * 8);
      const f32x4 a1 = *(const f32x4*)(xrow + kq * 8 + 4);
      const f32x4 a2 = *(const f32x4*)(xrow + 32 + kq * 8);
      const f32x4 a3 = *(const f32x4*)(xrow + 32 + kq * 8 + 4);
      h8 ax0, ax1;
#pragma unroll
      for (int j = 0; j < 4; ++j) {
        ax0[j] = (half_t)a0[j];
        ax0[4 + j] = (half_t)a1[j];
        ax1[j] = (half_t)a2[j];
        ax1[4 + j] = (half_t)a3[j];
      }
      PEMIT(ax0, ax1, 0)
    }
    const int i1 = (1 < Lm) ? 1 : Lm - 1;
    f32x4 xc0 = *(const f32x4*)(xrow + i1 * 64 + kq * 8);
    f32x4 xc1 = *(const f32x4*)(xrow + i1 * 64 + kq * 8 + 4);
    f32x4 xc2 = *(const f32x4*)(xrow + i1 * 64 + 32 + kq * 8);
    f32x4 xc3 = *(const f32x4*)(xrow + i1 * 64 + 32 + kq * 8 + 4);

    RBAR();  // prologue barrier (x(1) loads stay in flight)

    for (int t = 0; t < Lm; ++t) {
      // phase 1: cvt x(t+1) -> frags; issue x(t+2) loads
      h8 ax0, ax1;
#pragma unroll
      for (int j = 0; j < 4; ++j) {
        ax0[j] = (half_t)xc0[j];
        ax0[4 + j] = (half_t)xc1[j];
        ax1[j] = (half_t)xc2[j];
        ax1[4 + j] = (half_t)xc3[j];
      }
      const int t2 = (t + 2 < Lm) ? t + 2 : Lm - 1;
      const f32x4 xn0 = *(const f32x4*)(xrow + t2 * 64 + kq * 8);
      const f32x4 xn1 = *(const f32x4*)(xrow + t2 * 64 + kq * 8 + 4);
      const f32x4 xn2 = *(const f32x4*)(xrow + t2 * 64 + 32 + kq * 8);
      const f32x4 xn3 = *(const f32x4*)(xrow + t2 * 64 + 32 + kq * 8 + 4);

      RBAR();  // B1

      // phase 2: emit preact(t+1) into buf (t+1)&1
      PEMIT(ax0, ax1, (t + 1) & 1)
      xc0 = xn0; xc1 = xn1; xc2 = xn2; xc3 = xn3;

      RBAR();  // B2 (lgkmcnt(0): sPre writes visible; VMEM stays in flight)
    }
#undef PEMIT
  } else {
    // ===================== WRITER (1 wave) =================================
    const int row = l >> 3;          // 0..7 (all valid)
    const int c8 = (l & 7) * 8;      // 8-col octet
    const int L = SL[b0 + row];
    float* __restrict__ orow = OUT + (size_t)(b0 + row) * (T_ * D_) + c8;
    // A-layout: 8 consecutive cols of one row = 8 contiguous halfs
    const int slice = c8 >> 5;
    const int idx = (row + 16 * ((c8 & 31) >> 3)) * 8;
    const f32x4 zf4 = {0.f, 0.f, 0.f, 0.f};

    RBAR();  // prologue

    for (int t = 0; t < Lm; ++t) {
      // phase-1 window: sAh holds h(t-1); store output(t-1)
      if (t > 0) {
        const h8 hv = *(const h8*)&sAh[slice][idx];
        const bool ok = (t - 1) < L;
        f32x4 v0, v1;
#pragma unroll
        for (int j = 0; j < 4; ++j) {
          v0[j] = ok ? (float)hv[j] : 0.0f;
          v1[j] = ok ? (float)hv[4 + j] : 0.0f;
        }
        *(f32x4*)(orow + (size_t)(t - 1) * 64) = v0;
        *(f32x4*)(orow + (size_t)(t - 1) * 64 + 4) = v1;
      }
      RBAR();  // B1
      RBAR();  // B2 (store-acks never drained)
    }
    // flush h(Lm-1) + zero tail
    {
      const h8 hv = *(const h8*)&sAh[slice][idx];
      const bool ok = (Lm - 1) < L;
      f32x4 v0, v1;
#pragma unroll
      for (int j = 0; j < 4; ++j) {
        v0[j] = ok ? (float)hv[j] : 0.0f;
        v1[j] = ok ? (float)hv[4 + j] : 0.0f;
      }
      *(f32x4*)(orow + (size_t)(Lm - 1) * 64) = v0;
      *(f32x4*)(orow + (size_t)(Lm - 1) * 64 + 4) = v1;
      for (int tz = Lm; tz < T_; ++tz) {
        *(f32x4*)(orow + (size_t)tz * 64) = zf4;
        *(f32x4*)(orow + (size_t)tz * 64 + 4) = zf4;
      }
    }
  }
}

extern "C" void kernel_launch(void* const* d_in, const int* in_sizes, int n_in,
                              void* d_out, int out_size, void* d_ws, size_t ws_size,
                              hipStream_t stream) {
  (void)in_sizes; (void)n_in; (void)d_ws; (void)ws_size; (void)out_size;
  const float* X  = (const float*)d_in[0];
  const int*   SL = (const int*)d_in[1];
  const float* A  = (const float*)d_in[2];
  const float* Wg = (const float*)d_in[3];
  const float* bg = (const float*)d_in[4];
  const float* Wc = (const float*)d_in[5];
  const float* bc = (const float*)d_in[6];
  float* O = (float*)d_out;

  augru_pcw2<<<NBLK, NTHR, 0, stream>>>(X, SL, A, Wg, bg, Wc, bc, O);
}